// Round 2
// baseline (365.077 us; speedup 1.0000x reference)
//
#include <hip/hip_runtime.h>
#include <math.h>

#define D 128
#define H 4
#define DHEAD 32

#define BM 64
#define BN 64
#define BK 16

// ---------------------------------------------------------------------------
// Fused projection GEMM: Y = x @ W^T + b for {Wq,Wk,Wv,Wskip}.
// q,k,v go to ws as [N][384] (cols 0-127 q, 128-255 k, 256-383 v).
// skip tile writes outbase = x + x@Wskip^T + bskip directly to d_out.
// Grid: (8 col-tiles, ceil(N/64) row-tiles), 256 threads.
// ---------------------------------------------------------------------------
__global__ __launch_bounds__(256) void gemm_qkvs(
    const float* __restrict__ x,
    const float* __restrict__ Wq, const float* __restrict__ bq,
    const float* __restrict__ Wk, const float* __restrict__ bk,
    const float* __restrict__ Wv, const float* __restrict__ bv,
    const float* __restrict__ Wsk, const float* __restrict__ bsk,
    float* __restrict__ qkv, float* __restrict__ outbase, int N)
{
    __shared__ float As[BK][BM + 4];
    __shared__ float Bs[BK][BN + 4];

    const int t  = threadIdx.x;
    const int bx = blockIdx.x;     // 0..7 : which 64-col tile of the 512 outputs
    const int by = blockIdx.y;     // row tile
    const int which = bx >> 1;     // 0=q 1=k 2=v 3=skip
    const float* W    = (which == 0) ? Wq : (which == 1) ? Wk : (which == 2) ? Wv : Wsk;
    const float* bias = (which == 0) ? bq : (which == 1) ? bk : (which == 2) ? bv : bsk;
    const int obase   = (bx & 1) * BN;   // 0 or 64 inside the 128-col matrix
    const int rowbase = by * BM;

    const int lr = t >> 2;          // 0..63 row (A) / out-row (B) for loads
    const int lk = (t & 3) * 4;     // k offset within BK (float4)

    const int tm = t >> 4;          // 0..15 -> rows tm*4..tm*4+3
    const int tn = t & 15;          // 0..15 -> cols tn*4..tn*4+3

    float acc[4][4] = {};

    for (int kb = 0; kb < D; kb += BK) {
        int gr = rowbase + lr;
        float4 av = make_float4(0.f, 0.f, 0.f, 0.f);
        if (gr < N) av = *(const float4*)(x + (size_t)gr * D + kb + lk);
        As[lk + 0][lr] = av.x; As[lk + 1][lr] = av.y;
        As[lk + 2][lr] = av.z; As[lk + 3][lr] = av.w;

        float4 wv4 = *(const float4*)(W + (size_t)(obase + lr) * D + kb + lk);
        Bs[lk + 0][lr] = wv4.x; Bs[lk + 1][lr] = wv4.y;
        Bs[lk + 2][lr] = wv4.z; Bs[lk + 3][lr] = wv4.w;
        __syncthreads();

        #pragma unroll
        for (int k = 0; k < BK; ++k) {
            float a0 = As[k][tm * 4 + 0], a1 = As[k][tm * 4 + 1];
            float a2 = As[k][tm * 4 + 2], a3 = As[k][tm * 4 + 3];
            float b0 = Bs[k][tn * 4 + 0], b1 = Bs[k][tn * 4 + 1];
            float b2 = Bs[k][tn * 4 + 2], b3 = Bs[k][tn * 4 + 3];
            acc[0][0] += a0 * b0; acc[0][1] += a0 * b1; acc[0][2] += a0 * b2; acc[0][3] += a0 * b3;
            acc[1][0] += a1 * b0; acc[1][1] += a1 * b1; acc[1][2] += a1 * b2; acc[1][3] += a1 * b3;
            acc[2][0] += a2 * b0; acc[2][1] += a2 * b1; acc[2][2] += a2 * b2; acc[2][3] += a2 * b3;
            acc[3][0] += a3 * b0; acc[3][1] += a3 * b1; acc[3][2] += a3 * b2; acc[3][3] += a3 * b3;
        }
        __syncthreads();
    }

    const int col0 = obase + tn * 4;   // col within the 128-col matrix
    #pragma unroll
    for (int i = 0; i < 4; ++i) {
        int gr = rowbase + tm * 4 + i;
        if (gr >= N) continue;
        float4 o4;
        o4.x = acc[i][0] + bias[col0 + 0];
        o4.y = acc[i][1] + bias[col0 + 1];
        o4.z = acc[i][2] + bias[col0 + 2];
        o4.w = acc[i][3] + bias[col0 + 3];
        if (which < 3) {
            *(float4*)(qkv + (size_t)gr * 384 + which * D + col0) = o4;
        } else {
            float4 xv = *(const float4*)(x + (size_t)gr * D + col0);
            o4.x += xv.x; o4.y += xv.y; o4.z += xv.z; o4.w += xv.w;
            *(float4*)(outbase + (size_t)gr * D + col0) = o4;
        }
    }
}

// ---------------------------------------------------------------------------
// Zero kernel (capture-safe replacement for hipMemsetAsync).
// ---------------------------------------------------------------------------
__global__ void zero_kernel(int* __restrict__ p, int n)
{
    int i = blockIdx.x * 256 + threadIdx.x;
    if (i < n) p[i] = 0;
}

// ---------------------------------------------------------------------------
// CSR build: histogram -> exclusive scan (2-level) -> scatter edges by dst.
// ---------------------------------------------------------------------------
__global__ void hist_kernel(const int* __restrict__ dst, int* __restrict__ counts, int E)
{
    int e = blockIdx.x * 256 + threadIdx.x;
    if (e < E) atomicAdd(&counts[dst[e]], 1);
}

__global__ __launch_bounds__(1024) void scan_blocks(
    const int* __restrict__ counts, int* __restrict__ offsets,
    int* __restrict__ partials, int n)
{
    __shared__ int sm[1024];
    int tid = threadIdx.x;
    int i = blockIdx.x * 1024 + tid;
    int v = (i < n) ? counts[i] : 0;
    sm[tid] = v;
    __syncthreads();
    for (int off = 1; off < 1024; off <<= 1) {
        int tv = (tid >= off) ? sm[tid - off] : 0;
        __syncthreads();
        sm[tid] += tv;
        __syncthreads();
    }
    if (i < n) offsets[i] = sm[tid] - v;     // exclusive
    if (tid == 1023) partials[blockIdx.x] = sm[1023];
}

__global__ void scan_partials(int* partials, int nb)
{
    if (threadIdx.x == 0 && blockIdx.x == 0) {
        int s = 0;
        for (int b = 0; b < nb; ++b) { int t = partials[b]; partials[b] = s; s += t; }
    }
}

__global__ __launch_bounds__(1024) void scan_add(
    int* __restrict__ offsets, int* __restrict__ cursor,
    const int* __restrict__ partials, int n)
{
    int i = blockIdx.x * 1024 + threadIdx.x;
    if (i < n) {
        int v = offsets[i] + partials[blockIdx.x];
        offsets[i] = v;
        cursor[i]  = v;
    }
}

__global__ void scatter_kernel(const int* __restrict__ src, const int* __restrict__ dst,
                               int* __restrict__ cursor, int* __restrict__ edge_src, int E)
{
    int e = blockIdx.x * 256 + threadIdx.x;
    if (e < E) {
        int p = atomicAdd(&cursor[dst[e]], 1);
        edge_src[p] = src[e];
    }
}

// ---------------------------------------------------------------------------
// Attention: one 64-lane wave per destination node. Each lane owns 2 of the
// 128 feature dims; head h = lane>>4 (16 lanes * 2 dims = 32 dims per head).
// Online softmax over the node's incoming edges; epilogue adds into base
// (x + skip) already resident in d_out.
// ---------------------------------------------------------------------------
__global__ __launch_bounds__(256) void attn_kernel(
    const float* __restrict__ qkv, const int* __restrict__ counts,
    const int* __restrict__ offsets, const int* __restrict__ edge_src,
    float* __restrict__ out, int N)
{
    const int lane = threadIdx.x & 63;
    const int wv   = threadIdx.x >> 6;
    const int i    = blockIdx.x * 4 + wv;
    if (i >= N) return;

    const float scale = 0.17677669529663687f;   // 1/sqrt(32)
    float2 q2 = *(const float2*)(qkv + (size_t)i * 384 + 2 * lane);
    const float q0 = q2.x * scale, q1 = q2.y * scale;

    float m = -INFINITY, l = 0.f, a0 = 0.f, a1 = 0.f;
    const int beg = offsets[i];
    const int cnt = counts[i];

    for (int e = 0; e < cnt; ++e) {
        int j = edge_src[beg + e];
        const float* base = qkv + (size_t)j * 384;
        float2 k2 = *(const float2*)(base + 128 + 2 * lane);
        float dot = q0 * k2.x + q1 * k2.y;
        dot += __shfl_xor(dot, 1);
        dot += __shfl_xor(dot, 2);
        dot += __shfl_xor(dot, 4);
        dot += __shfl_xor(dot, 8);
        float mn = fmaxf(m, dot);
        float p  = __expf(dot - mn);
        float sc = __expf(m - mn);     // first edge: exp(-inf)=0
        float2 v2 = *(const float2*)(base + 256 + 2 * lane);
        l  = l  * sc + p;
        a0 = a0 * sc + p * v2.x;
        a1 = a1 * sc + p * v2.y;
        m = mn;
    }

    float inv = 1.0f / (l + 1e-16f);    // cnt==0 -> a=0 -> out=base
    float2* orow = (float2*)(out + (size_t)i * D);
    float2 b2 = orow[lane];
    b2.x += a0 * inv;
    b2.y += a1 * inv;
    orow[lane] = b2;
}

// ---------------------------------------------------------------------------
extern "C" void kernel_launch(void* const* d_in, const int* in_sizes, int n_in,
                              void* d_out, int out_size, void* d_ws, size_t ws_size,
                              hipStream_t stream)
{
    const float* x   = (const float*)d_in[0];
    const int*   ei  = (const int*)d_in[1];    // [2][E], row0=src, row1=dst
    const float* Wq  = (const float*)d_in[2];
    const float* bq  = (const float*)d_in[3];
    const float* Wk  = (const float*)d_in[4];
    const float* bk  = (const float*)d_in[5];
    const float* Wv  = (const float*)d_in[6];
    const float* bv  = (const float*)d_in[7];
    const float* Wsk = (const float*)d_in[8];
    const float* bsk = (const float*)d_in[9];
    float* out = (float*)d_out;

    const int N = in_sizes[0] / D;
    const int E = in_sizes[1] / 2;

    // workspace layout (~81 MB)
    char* ws = (char*)d_ws;
    size_t o = 0;
    float* qkv     = (float*)(ws + o); o += (size_t)N * 384 * sizeof(float);
    int*   counts  = (int*)(ws + o);   o += (size_t)N * sizeof(int);
    int*   offsets = (int*)(ws + o);   o += (size_t)N * sizeof(int);
    int*   cursor  = (int*)(ws + o);   o += (size_t)N * sizeof(int);
    int*   partials= (int*)(ws + o);   o += 1024;
    int*   edge_src= (int*)(ws + o);   o += (size_t)E * sizeof(int);

    // capture-safe zero of counts (no hipMemsetAsync inside graph capture)
    zero_kernel<<<(N + 255) / 256, 256, 0, stream>>>(counts, N);

    dim3 gemm_grid(8, (N + BM - 1) / BM);
    gemm_qkvs<<<gemm_grid, 256, 0, stream>>>(x, Wq, bq, Wk, bk, Wv, bv, Wsk, bsk,
                                             qkv, out, N);

    hist_kernel<<<(E + 255) / 256, 256, 0, stream>>>(ei + E, counts, E);

    int nb = (N + 1023) / 1024;
    scan_blocks<<<nb, 1024, 0, stream>>>(counts, offsets, partials, N);
    scan_partials<<<1, 64, 0, stream>>>(partials, nb);
    scan_add<<<nb, 1024, 0, stream>>>(offsets, cursor, partials, N);

    scatter_kernel<<<(E + 255) / 256, 256, 0, stream>>>(ei, ei + E, cursor, edge_src, E);

    attn_kernel<<<(N + 3) / 4, 256, 0, stream>>>(qkv, counts, offsets, edge_src, out, N);
}

// Round 3
// 224.683 us; speedup vs baseline: 1.6249x; 1.6249x over previous
//
#include <hip/hip_runtime.h>
#include <math.h>

#define D 128

typedef __attribute__((ext_vector_type(8))) short short8;
typedef __attribute__((ext_vector_type(4))) float f32x4;

__device__ __forceinline__ ushort f2bf(float f) {
    uint u = __float_as_uint(f);
    u += 0x7FFFu + ((u >> 16) & 1u);       // round-to-nearest-even
    return (ushort)(u >> 16);
}
__device__ __forceinline__ float bf2f(ushort h) { return __uint_as_float(((uint)h) << 16); }
__device__ __forceinline__ float lo2f(uint u) { return __uint_as_float(u << 16); }
__device__ __forceinline__ float hi2f(uint u) { return __uint_as_float(u & 0xFFFF0000u); }

// ---------------------------------------------------------------------------
// Convert x (N*128) and the 4 weight matrices (4*128*128) to bf16.
// xb: [N][128] bf16.  wb: [4][128][128] bf16 (q,k,v,skip).
// ---------------------------------------------------------------------------
__global__ void convert_kernel(
    const float* __restrict__ x,
    const float* __restrict__ Wq, const float* __restrict__ Wk,
    const float* __restrict__ Wv, const float* __restrict__ Ws,
    ushort* __restrict__ xb, ushort* __restrict__ wb, int nx4)
{
    int i = blockIdx.x * 256 + threadIdx.x;
    if (i < nx4) {
        float4 f = ((const float4*)x)[i];
        ushort4 h;
        h.x = f2bf(f.x); h.y = f2bf(f.y); h.z = f2bf(f.z); h.w = f2bf(f.w);
        ((ushort4*)xb)[i] = h;
    } else if (i < nx4 + 16384) {           // 4 matrices * 4096 float4
        int wi = i - nx4;
        int m = wi >> 12;
        const float* W = (m == 0) ? Wq : (m == 1) ? Wk : (m == 2) ? Wv : Ws;
        float4 f = ((const float4*)W)[wi & 4095];
        ushort4 h;
        h.x = f2bf(f.x); h.y = f2bf(f.y); h.z = f2bf(f.z); h.w = f2bf(f.w);
        ((ushort4*)wb)[wi] = h;
    }
}

// ---------------------------------------------------------------------------
// MFMA projection GEMM. Block = 512 threads = 8 waves, 64 rows per block.
// Wave w: matrix = w>>1 (0=q,1=k,2=v,3=skip), cols (w&1)*64 .. +63.
// y = x @ W^T: A-frag = x rows (bf16x8 contiguous), B-frag = W rows
// (B^T layout, m92-verified). C layout: col=lane&15, row=(lane>>4)*4+reg.
// Epilogue stages each 16-row chunk through a swizzled per-wave LDS slab
// to produce coalesced row-major stores.
// qkv layout [N][384] bf16: q at 0..127; k/v interleaved at 128..383 as
// (k[2d],k[2d+1],v[2d],v[2d+1]) per d=0..63  -> attn reads one uint2/lane.
// ---------------------------------------------------------------------------
__global__ __launch_bounds__(512) void mfma_qkvs(
    const ushort* __restrict__ xb, const ushort* __restrict__ wb,
    const float* __restrict__ bq, const float* __restrict__ bk,
    const float* __restrict__ bv, const float* __restrict__ bsk,
    const float* __restrict__ x,
    ushort* __restrict__ qkv, float* __restrict__ out, int N)
{
    __shared__ __align__(16) ushort stg[8][16][64];

    const int t = threadIdx.x;
    const int w = t >> 6, l = t & 63;
    const int mat = w >> 1;
    const int col0 = (w & 1) * 64;
    const int r0 = blockIdx.x * 64;
    const int lr = l & 15, lg = l >> 4;

    const ushort* W = wb + (size_t)mat * (D * D);
    const float* bias = (mat == 0) ? bq : (mat == 1) ? bk : (mat == 2) ? bv : bsk;

    float bi[4];
    #pragma unroll
    for (int ct = 0; ct < 4; ++ct) bi[ct] = bias[col0 + ct * 16 + lr];

    f32x4 acc[4][4];
    #pragma unroll
    for (int rt = 0; rt < 4; ++rt)
        #pragma unroll
        for (int ct = 0; ct < 4; ++ct)
            acc[rt][ct] = (f32x4){0.f, 0.f, 0.f, 0.f};

    int arow[4];
    #pragma unroll
    for (int rt = 0; rt < 4; ++rt) arow[rt] = min(r0 + rt * 16 + lr, N - 1);

    #pragma unroll
    for (int ks = 0; ks < 4; ++ks) {
        const int kofs = ks * 32 + lg * 8;
        short8 a[4], b[4];
        #pragma unroll
        for (int rt = 0; rt < 4; ++rt)
            a[rt] = *(const short8*)(xb + (size_t)arow[rt] * D + kofs);
        #pragma unroll
        for (int ct = 0; ct < 4; ++ct)
            b[ct] = *(const short8*)(W + (size_t)(col0 + ct * 16 + lr) * D + kofs);
        #pragma unroll
        for (int rt = 0; rt < 4; ++rt)
            #pragma unroll
            for (int ct = 0; ct < 4; ++ct)
                acc[rt][ct] = __builtin_amdgcn_mfma_f32_16x16x32_bf16(
                    a[rt], b[ct], acc[rt][ct], 0, 0, 0);
    }

    // Epilogue: 4 chunks of 16 rows; same-wave LDS write->read (in-order DS pipe).
    for (int rt = 0; rt < 4; ++rt) {
        #pragma unroll
        for (int ct = 0; ct < 4; ++ct) {
            const int colL = ct * 16 + lr;
            const int cch = colL >> 3, cin = colL & 7;
            #pragma unroll
            for (int r = 0; r < 4; ++r) {
                const int rowL = lg * 4 + r;
                stg[w][rowL][((cch ^ (rowL & 7)) << 3) + cin] =
                    f2bf(acc[rt][ct][r] + bi[ct]);
            }
        }
        #pragma unroll
        for (int rr = 0; rr < 2; ++rr) {
            const int rowL = rr * 8 + (l >> 3);
            const int c = l & 7;
            const int p = c ^ (rowL & 7);
            uint4 hv = *(const uint4*)&stg[w][rowL][p << 3];
            const int row_g = r0 + rt * 16 + rowL;
            if (row_g < N) {
                if (mat == 0) {
                    *(uint4*)(qkv + (size_t)row_g * 384 + col0 + c * 8) = hv;
                } else if (mat < 3) {
                    // interleaved k/v pairs: elems 128 + 4*d (+2 for v)
                    uint* du = (uint*)(qkv + (size_t)row_g * 384 + 128
                                       + 2 * col0 + 16 * c + ((mat == 2) ? 2 : 0));
                    const uint* hu = (const uint*)&hv;
                    #pragma unroll
                    for (int tt = 0; tt < 4; ++tt) du[tt * 2] = hu[tt];
                } else {
                    const ushort* hs = (const ushort*)&hv;
                    const float4* xr = (const float4*)(x + (size_t)row_g * D + col0 + c * 8);
                    float4 x0 = xr[0], x1 = xr[1];
                    float4 o0, o1;
                    o0.x = x0.x + bf2f(hs[0]); o0.y = x0.y + bf2f(hs[1]);
                    o0.z = x0.z + bf2f(hs[2]); o0.w = x0.w + bf2f(hs[3]);
                    o1.x = x1.x + bf2f(hs[4]); o1.y = x1.y + bf2f(hs[5]);
                    o1.z = x1.z + bf2f(hs[6]); o1.w = x1.w + bf2f(hs[7]);
                    float4* orow = (float4*)(out + (size_t)row_g * D + col0 + c * 8);
                    orow[0] = o0; orow[1] = o1;
                }
            }
        }
    }
}

// ---------------------------------------------------------------------------
// CSR build
// ---------------------------------------------------------------------------
__global__ void zero_kernel(int* __restrict__ p, int n)
{
    int i = blockIdx.x * 256 + threadIdx.x;
    if (i < n) p[i] = 0;
}

__global__ void hist_kernel(const int* __restrict__ dst, int* __restrict__ counts, int E)
{
    int e = blockIdx.x * 256 + threadIdx.x;
    if (e < E) atomicAdd(&counts[dst[e]], 1);
}

__global__ __launch_bounds__(1024) void scan_blocks(
    const int* __restrict__ counts, int* __restrict__ offsets,
    int* __restrict__ partials, int n)
{
    __shared__ int sm[1024];
    int tid = threadIdx.x;
    int i = blockIdx.x * 1024 + tid;
    int v = (i < n) ? counts[i] : 0;
    sm[tid] = v;
    __syncthreads();
    for (int off = 1; off < 1024; off <<= 1) {
        int tv = (tid >= off) ? sm[tid - off] : 0;
        __syncthreads();
        sm[tid] += tv;
        __syncthreads();
    }
    if (i < n) offsets[i] = sm[tid] - v;
    if (tid == 1023) partials[blockIdx.x] = sm[1023];
}

// single-wave shuffle scan over block partials (nb ~ 49)
__global__ void scan_partials(int* __restrict__ p, int nb)
{
    const int l = threadIdx.x;   // 64 threads
    int base = 0;
    for (int s = 0; s < nb; s += 64) {
        int idx = s + l;
        int v = (idx < nb) ? p[idx] : 0;
        const int orig = v;
        #pragma unroll
        for (int off = 1; off < 64; off <<= 1) {
            int tv = __shfl_up(v, off);
            if (l >= off) v += tv;
        }
        if (idx < nb) p[idx] = base + v - orig;   // exclusive
        base += __shfl(v, 63);
    }
}

__global__ __launch_bounds__(1024) void scan_add(
    int* __restrict__ offsets, int* __restrict__ cursor,
    const int* __restrict__ partials, int n)
{
    int i = blockIdx.x * 1024 + threadIdx.x;
    if (i < n) {
        int v = offsets[i] + partials[blockIdx.x];
        offsets[i] = v;
        cursor[i]  = v;
    }
}

__global__ void scatter_kernel(const int* __restrict__ src, const int* __restrict__ dst,
                               int* __restrict__ cursor, int* __restrict__ edge_src, int E)
{
    int e = blockIdx.x * 256 + threadIdx.x;
    if (e < E) {
        int p = atomicAdd(&cursor[dst[e]], 1);
        edge_src[p] = src[e];
    }
}

// ---------------------------------------------------------------------------
// Attention: one wave per destination node, lane owns dims 2*lane..2*lane+1,
// head = lane>>4. bf16 k/v interleaved -> one 8B load per edge per lane.
// Software-pipelined: edge index 2 deep, k/v 1 deep.
// ---------------------------------------------------------------------------
__global__ __launch_bounds__(256) void attn_kernel(
    const ushort* __restrict__ qkv, const int* __restrict__ counts,
    const int* __restrict__ offsets, const int* __restrict__ edge_src,
    float* __restrict__ out, int N)
{
    const int lane = threadIdx.x & 63;
    const int wv   = threadIdx.x >> 6;
    const int i    = blockIdx.x * 4 + wv;
    if (i >= N) return;

    const float scale = 0.17677669529663687f;   // 1/sqrt(32)
    const uint qb = *(const uint*)(qkv + (size_t)i * 384 + 2 * lane);
    const float q0 = lo2f(qb) * scale, q1 = hi2f(qb) * scale;

    float m = -INFINITY, l = 0.f, a0 = 0.f, a1 = 0.f;
    const int beg = offsets[i];
    const int cnt = counts[i];

    if (cnt > 0) {
        int j1 = edge_src[beg];
        uint2 kv = *(const uint2*)(qkv + (size_t)j1 * 384 + 128 + 4 * lane);
        j1 = (cnt > 1) ? edge_src[beg + 1] : j1;
        for (int e = 0; e < cnt; ++e) {
            const int j2 = edge_src[beg + min(e + 2, cnt - 1)];
            const uint2 kvn = *(const uint2*)(qkv + (size_t)j1 * 384 + 128 + 4 * lane);
            float dot = q0 * lo2f(kv.x) + q1 * hi2f(kv.x);
            dot += __shfl_xor(dot, 1);
            dot += __shfl_xor(dot, 2);
            dot += __shfl_xor(dot, 4);
            dot += __shfl_xor(dot, 8);
            const float mn = fmaxf(m, dot);
            const float p  = __expf(dot - mn);
            const float sc = __expf(m - mn);
            l  = l  * sc + p;
            a0 = a0 * sc + p * lo2f(kv.y);
            a1 = a1 * sc + p * hi2f(kv.y);
            m = mn;
            kv = kvn; j1 = j2;
        }
    }

    const float inv = 1.0f / (l + 1e-16f);
    float2* orow = (float2*)(out + (size_t)i * D);
    float2 b2 = orow[lane];
    b2.x += a0 * inv;
    b2.y += a1 * inv;
    orow[lane] = b2;
}

// ---------------------------------------------------------------------------
extern "C" void kernel_launch(void* const* d_in, const int* in_sizes, int n_in,
                              void* d_out, int out_size, void* d_ws, size_t ws_size,
                              hipStream_t stream)
{
    const float* x   = (const float*)d_in[0];
    const int*   ei  = (const int*)d_in[1];    // [2][E], row0=src, row1=dst
    const float* Wq  = (const float*)d_in[2];
    const float* bq  = (const float*)d_in[3];
    const float* Wk  = (const float*)d_in[4];
    const float* bk  = (const float*)d_in[5];
    const float* Wv  = (const float*)d_in[6];
    const float* bv  = (const float*)d_in[7];
    const float* Wsk = (const float*)d_in[8];
    const float* bsk = (const float*)d_in[9];
    float* out = (float*)d_out;

    const int N = in_sizes[0] / D;
    const int E = in_sizes[1] / 2;

    // workspace layout (~55 MB)
    char* ws = (char*)d_ws;
    size_t o = 0;
    ushort* xb      = (ushort*)(ws + o); o += (size_t)N * D * sizeof(ushort);
    ushort* wb      = (ushort*)(ws + o); o += (size_t)4 * D * D * sizeof(ushort);
    ushort* qkv     = (ushort*)(ws + o); o += (size_t)N * 384 * sizeof(ushort);
    o = (o + 255) & ~(size_t)255;
    int*   counts   = (int*)(ws + o);    o += (size_t)N * sizeof(int);
    int*   offsets  = (int*)(ws + o);    o += (size_t)N * sizeof(int);
    int*   cursor   = (int*)(ws + o);    o += (size_t)N * sizeof(int);
    int*   partials = (int*)(ws + o);    o += 4096;
    int*   edge_src = (int*)(ws + o);    o += (size_t)E * sizeof(int);

    const int nx4 = N * D / 4;
    convert_kernel<<<(nx4 + 16384 + 255) / 256, 256, 0, stream>>>(
        x, Wq, Wk, Wv, Wsk, xb, wb, nx4);

    mfma_qkvs<<<(N + 63) / 64, 512, 0, stream>>>(
        xb, wb, bq, bk, bv, bsk, x, qkv, out, N);

    zero_kernel<<<(N + 255) / 256, 256, 0, stream>>>(counts, N);
    hist_kernel<<<(E + 255) / 256, 256, 0, stream>>>(ei + E, counts, E);

    int nb = (N + 1023) / 1024;
    scan_blocks<<<nb, 1024, 0, stream>>>(counts, offsets, partials, N);
    scan_partials<<<1, 64, 0, stream>>>(partials, nb);
    scan_add<<<nb, 1024, 0, stream>>>(offsets, cursor, partials, N);
    scatter_kernel<<<(E + 255) / 256, 256, 0, stream>>>(ei, ei + E, cursor, edge_src, E);

    attn_kernel<<<(N + 3) / 4, 256, 0, stream>>>(qkv, counts, offsets, edge_src, out, N);
}